// Round 17
// baseline (92.532 us; speedup 1.0000x reference)
//
#include <hip/hip_runtime.h>
#include <stdint.h>

// HamiltonianFlow: x [256, 8, 32, 2] (q,p); H = 0.5*sum(p^2) + MLP(q).
// dq/dt = p, dp/dt = -W u(z), z = W^T q + b1, u = (1-tanh^2(z)).*W2.
// z-space iteration with M = W^T W (R15-R23 verified).
//
// R39 = R38 (green: ~35.5us dispatch, 87.9 bench, bit-identical absmax)
// + WBT-GATHER HOIST (single scheduling-only change). The epilogue's
// wBt fragment (64x scalar ds_read_u16/lane, column gather from wldsT,
// bank-conflicted) ran AFTER the loop with nothing to hide it. wldsT is
// read-only after the M-build and ubuf is a distinct LDS object (no
// alias), so the gather moves ABOVE the main loop: the conflicted reads
// drain concurrently with the first exchanges. +32 VGPR (52->~84, under
// the 128/wave budget at 4 waves/SIMD; R29b spill tripwire=WRITE_SIZE).
// A keep-alive asm pin prevents LLVM sinking the loads back down.
// Values bit-identical. (R37 measured the GLOBAL wBt variant at -4.4us:
// 1024B-strided lane gather, 64 cache lines/instr -> keep LDS source.)
//
// R38: TAYLOR STAGE EVALS - the 4 stage z's of a step differ from base
// zp by d ~ 3e-3. One eval: r = rcp(e^{2zp}+1), ua = w4*(r-r^2),
// u' = -tanh*ua (exact); uA = 3ua + u'*(db+dc); uB = 6ua + u'*(2(db+dc)
// +dd); db = 2hdt*Pp, dc = db + KC1n*AL, dd = 2dt*Pp + KC2n*AL.
// Taylor err ~1e-6 abs, >100x below uA's f16 quantum. 2 exp/lane/exch.
//
// R35/R33: COMBO-LINEARITY - advance/predictor need only A_j, B_j and
// Y_i = M u_i => pre-sum u's: row(2j) = uA_j, row(2j+1) = uB_j; 16 rows
// = 8 steps/exchange, 12 exchanges (H=8 measured optimum). Tail steps
// 96-99 are S-ONLY (dead-code eliminated).
// Exact 8-step advance: z += 8dt*P - dtdt6*SV8;  P -= dt6*SB8;
//   SB8 = sum B_j;  SV8 = sum (7-j)B_j + sum A_j
//   pred step j: Pp = P - (j/8)dt6*SBp;
//     zp2 = 2z + 2j*dt*P + dtdt6*j(8-j)/8*SBp - dtdt6*(j/4)*SVp
// Lane (quad q) owns steps j1=2q, j2=2q+1 (C rows 4q..4q+3); V-partial
// = fma(7-j1, B1+B2, A1+A2-B2); 2 bfly4 per 8 steps. S: sp=uB, sq=uA.
//
// R30 substrate: 16 waves x 1 tile (1024 thr), in-kernel W^T staging +
// M-build, ONE barrier per exchange (R24 double-buffer race argument),
// R30 bank-swizzle, permlane bfly4, mscr UNION ubuf (upool).
// FULL unroll on every reg-array access (R4: dynamic index => scratch).
// Numerics: f16 storage (W, M, uA/uB, S), fp32 MFMA accum + fp32 z/P.

typedef _Float16 v8h __attribute__((ext_vector_type(8)));
typedef float v4f __attribute__((ext_vector_type(4)));

#define NFULL 12  // full 8-step exchanges; steps 96-99 = eval-only tail
#define WS 264    // wldsT row stride (f16): row = one W-COLUMN, 16B-aligned
#define US 272    // ubuf row stride, f16 (544 B == 32 mod 128)

// D(+=C) in VGPRs, A (packed-vector frag) in VGPRs, B (M-frag) from AGPRs.
#define MFMA_AV(C, A, B) \
    asm("v_mfma_f32_16x16x32_f16 %0, %1, %2, %0" : "+v"(C) : "v"(A), "a"(B))

// 4-group butterfly sum over lanes {l, l^16, l^32, l^48}, pure VALU.
__device__ __forceinline__ float bfly4(float x) {
    float a = x, b = x;
    asm("v_permlane16_swap_b32 %0, %1" : "+v"(a), "+v"(b));
    float s = a + b;
    float c = s, d = s;
    asm("v_permlane32_swap_b32 %0, %1" : "+v"(c), "+v"(d));
    return c + d;
}

__global__ __launch_bounds__(1024, 4)
void ham_kernel(const float* __restrict__ x0, const float* __restrict__ W1,
                const float* __restrict__ b1, const float* __restrict__ W2,
                float* __restrict__ out)
{
    __shared__ __align__(16)  _Float16 wldsT[256 * WS];  // 135168 B: W^T (f16)
    __shared__ __align__(128) char     upool[20480];     // mscr UNION ubuf
    float*    mscr = (float*)upool;                      // setup only
    _Float16* ubuf = (_Float16*)upool;                   // 2 x 16 rows x US

    const int t = threadIdx.x;
    const int w = t >> 6;          // wave 0..15: owns tile w (16 comps)
    const int l = t & 63;
    const int quad = l >> 4;       // owns steps 2*quad, 2*quad+1
    const int s = l & 15;          // owned column / A-row
    const int c0 = 16 * w + s;     // owned component
    const int blk = blockIdx.x;
    const int kq = 8 * quad;
    const int sel = (s & 3) * US;  // prologue/epilogue A-row select (rows 0-3)

    // ---- stage W^T -> LDS f16: wldsT[c][r] = W[r][c] ----
    {
        const int c = t & 255;
        const int rbase = (t >> 8) * 64;   // 4 quarters x 64 rows
        #pragma unroll 1
        for (int r0 = 0; r0 < 64; r0 += 8) {
            v8h h;
            #pragma unroll
            for (int j = 0; j < 8; ++j)
                h[j] = (_Float16)W1[(rbase + r0 + j) * 256 + c];
            *(v8h*)(wldsT + c * WS + rbase + r0) = h;   // b128, one-time
        }
    }
    __syncthreads();

    // ---- wF: own-column W^T frag (B-op), contiguous b128 from wldsT ----
    v8h wF0[8];
    #pragma unroll
    for (int kk = 0; kk < 8; ++kk)
        wF0[kk] = *(const v8h*)(wldsT + c0 * WS + 32 * kk + kq);

    // ---- build M = W^T W column-block frags wM0 (B-op: M[k][c0]) ----
    v8h wM0[8];
    float* scr0 = mscr + w * 320;
    #pragma unroll
    for (int kb = 0; kb < 16; ++kb) {
        v8h aM[8];   // A[m=s][k=8quad+j] = wldsT[(16kb+s)*WS + 32kk+kq+j]
        #pragma unroll
        for (int kk = 0; kk < 8; ++kk)
            aM[kk] = *(const v8h*)(wldsT + (16 * kb + s) * WS + 32 * kk + kq);
        v4f D0 = {0.f,0.f,0.f,0.f};
        #pragma unroll
        for (int kk = 0; kk < 8; ++kk)
            D0 = __builtin_amdgcn_mfma_f32_16x16x32_f16(aM[kk], wF0[kk], D0, 0, 0, 0);
        *(v4f*)(scr0 + s * 20 + 4 * quad) = D0;
        asm volatile("s_waitcnt lgkmcnt(0)" ::: "memory");  // in-wave x-lane
        if ((quad >> 1) == (kb & 1)) {
            #pragma unroll
            for (int j = 0; j < 8; ++j)
                wM0[kb >> 1][j] = (_Float16)scr0[s * 20 + 8 * (quad & 1) + j];
        }
        asm volatile("s_waitcnt lgkmcnt(0)" ::: "memory");
    }
    __syncthreads();   // mscr reads (all waves) done before ubuf reuse

    // ---- HOISTED epilogue B-frag gather (R39): wldsT is read-only from
    //      here on and ubuf is a distinct LDS object -> safe to gather
    //      now; the conflicted reads drain under the first exchanges.
    //      wBt[kk][j] = W[c0][32kk+kq+j] = wldsT[(32kk+kq+j)*WS + c0] ----
    v8h wBt0[8];
    #pragma unroll
    for (int kk = 0; kk < 8; ++kk) {
        #pragma unroll
        for (int j = 0; j < 8; ++j)
            wBt0[kk][j] = wldsT[(32 * kk + kq + j) * WS + c0];
        asm volatile("" : "+v"(wBt0[kk]));   // pin: forbid sinking past loop
    }

    const float b1r0 = b1[c0];
    const float w4 = 4.f * W2[c0];
    float2 qp0 = ((const float2*)(x0 + (size_t)blk * 512))[c0];
    const float q0o0 = qp0.x, p0o0 = qp0.y;

    // ---- prologue: buf0 rows {q0, p0, 0, 0} -> z1 (C[0]), P (C[1]) ----
    if (quad == 0) {
        ubuf[c0] = (_Float16)q0o0;
        ubuf[US + c0] = (_Float16)p0o0;
        ubuf[2 * US + c0] = (_Float16)0.f;
        ubuf[3 * US + c0] = (_Float16)0.f;
    }
    __syncthreads();
    float z1, P;
    {
        const _Float16* ab = ubuf + sel + kq;
        v4f C0a = {0.f,0.f,0.f,0.f}, C0b = {0.f,0.f,0.f,0.f};
        #pragma unroll
        for (int kk = 0; kk < 8; kk += 2) {
            v8h a0 = *(const v8h*)(ab + 32 * kk);
            v8h a1 = *(const v8h*)(ab + 32 * (kk + 1));
            C0a = __builtin_amdgcn_mfma_f32_16x16x32_f16(a0, wF0[kk], C0a, 0, 0, 0);
            C0b = __builtin_amdgcn_mfma_f32_16x16x32_f16(a1, wF0[kk + 1], C0b, 0, 0, 0);
        }
        v4f C0s = C0a + C0b;
        z1 = C0s[0] + b1r0;  P = C0s[1];
    }
    __syncthreads();   // prologue reads done before u(0) overwrites buf0

    const float dt = 0.01f, hdt = 0.005f, dt6 = 0.01f / 6.f;
    const float dtdt6 = dt * dt6, hdt2 = hdt * hdt, dthdt = dt * hdt;
    const float K8dt = 8.f * dt;
    // steps j1 = 2q, j2 = 2q+1; horizon-8 predictor coefs (R29c-verified)
    const float j1 = 2.f * (float)quad, j2 = j1 + 1.f;
    const float cPn1 = -(j1 * 0.125f * dt6), cPn2 = -(j2 * 0.125f * dt6);
    const float Kz1a = 2.f * j1 * dt,        Kz1b = 2.f * j2 * dt;
    const float KB1 = dtdt6 * j1 * (8.f - j1) * 0.125f;
    const float KB2 = dtdt6 * j2 * (8.f - j2) * 0.125f;
    const float KVn1 = -(j1 * dtdt6 * 0.25f), KVn2 = -(j2 * dtdt6 * 0.25f);
    const float K2hdt = 2.f * hdt;
    const float K2dt  = 2.f * dt;
    const float KC1n = -(2.f * hdt2) / 3.f;   // dc: -2hdt^2 * (A/3) folded
    const float KC2n = -(2.f * dthdt) / 3.f;  // dd: -2*dt*hdt * (A/3) folded
    const float w71 = 7.f - j1;               // V = fma(w71, B1+B2, A1+A2-B2)

    // ---- ubuf addressing (R30 bank swizzle, kept) ----
    const int cw = c0 ^ (quad << 3);
    const int R0 = 4 * quad;
    const int wo0 = (R0 + 0) * US + cw;          // row 4q   = uA(j1)
    const int wo1 = (R0 + 1) * US + (cw ^ 32);   // row 4q+1 = uB(j1)
    const int wo2 = (R0 + 2) * US + cw;          // row 4q+2 = uA(j2)
    const int wo3 = (R0 + 3) * US + (cw ^ 32);   // row 4q+3 = uB(j2)
    const int sx = (s >> 2) & 3;
    const int rbase = s * US + 8 * (quad ^ sx);
    const int sodd = (s & 1) << 5;
    const _Float16* pe = ubuf + rbase + sodd;          // logical even kk
    const _Float16* po = ubuf + rbase + 32 - sodd;     // logical odd  kk

    // lag state (exchange 0: zeros -> benign one-time transient)
    float SBp = 0.f, SVp = 0.f;
    float AL1 = 0.f, AL2 = 0.f;    // own-step A-combo lags (Y1~Y2~A/3)
    float S1p = 0.f, S23p = 0.f;
    float cn1 = 99.f - j1;         // step n1 = 8e + j1; n2 = n1 + 1

    #pragma unroll 1
    for (int e = 0; e < NFULL; ++e) {
        const int bo = (e & 1) * (16 * US);   // double-buffer offset

        // ---- predict both steps; ONE eval each; Taylor combos ----
        float z1d = z1 + z1;
        float Pp1  = __builtin_fmaf(cPn1, SBp, P);
        float zp21 = __builtin_fmaf(Kz1a, P, z1d);
        zp21 = __builtin_fmaf(KB1, SBp, zp21);
        zp21 = __builtin_fmaf(KVn1, SVp, zp21);
        float Pp2  = __builtin_fmaf(cPn2, SBp, P);
        float zp22 = __builtin_fmaf(Kz1b, P, z1d);
        zp22 = __builtin_fmaf(KB2, SBp, zp22);
        zp22 = __builtin_fmaf(KVn2, SVp, zp22);

        float e1 = __expf(zp21);
        float r1 = __builtin_amdgcn_rcpf(e1 + 1.f);
        float ua1 = w4 * __builtin_fmaf(-r1, r1, r1);       // w4*(r-r^2)
        float th1 = __builtin_fmaf(-2.f, r1, 1.f);          // tanh(z)
        float up1 = th1 * ua1;                              // -du/d(2z)
        float db1 = K2hdt * Pp1;
        float dc1 = __builtin_fmaf(KC1n, AL1, db1);
        float dd1 = __builtin_fmaf(K2dt, Pp1, KC2n * AL1);
        float sA1 = db1 + dc1;
        float sB1 = __builtin_fmaf(2.f, sA1, dd1);
        float u3a1 = 3.f * ua1;
        float uA1 = __builtin_fmaf(-up1, sA1, u3a1);        // 3ua + u'*sA
        float uB1 = __builtin_fmaf(-up1, sB1, u3a1 + u3a1); // 6ua + u'*sB

        float e2 = __expf(zp22);
        float r2 = __builtin_amdgcn_rcpf(e2 + 1.f);
        float ua2 = w4 * __builtin_fmaf(-r2, r2, r2);
        float th2 = __builtin_fmaf(-2.f, r2, 1.f);
        float up2 = th2 * ua2;
        float db2 = K2hdt * Pp2;
        float dc2 = __builtin_fmaf(KC1n, AL2, db2);
        float dd2 = __builtin_fmaf(K2dt, Pp2, KC2n * AL2);
        float sA2 = db2 + dc2;
        float sB2 = __builtin_fmaf(2.f, sA2, dd2);
        float u3a2 = 3.f * ua2;
        float uA2 = __builtin_fmaf(-up2, sA2, u3a2);
        float uB2 = __builtin_fmaf(-up2, sB2, u3a2 + u3a2);

        ubuf[bo + wo0] = (_Float16)uA1;
        ubuf[bo + wo1] = (_Float16)uB1;
        ubuf[bo + wo2] = (_Float16)uA2;
        ubuf[bo + wo3] = (_Float16)uB2;
        __syncthreads();   // the ONLY barrier per exchange (8 steps)

        // ---- ONE MFMA block: {A1,B1,A2,B2} combos for own comp ----
        v4f C0s;
        {
            v4f C0a = {0.f,0.f,0.f,0.f}, C0b = {0.f,0.f,0.f,0.f};
            #pragma unroll
            for (int kk = 0; kk < 8; kk += 2) {
                v8h a0 = *(const v8h*)(pe + bo + 32 * kk);
                v8h a1 = *(const v8h*)(po + bo + 32 * kk);
                MFMA_AV(C0a, a0, wM0[kk]);
                MFMA_AV(C0b, a1, wM0[kk + 1]);
            }
            C0s = C0a + C0b;
        }
        // no second barrier: next exchange writes the OTHER buffer (R24).

        // ---- EXACT 8-step advance via 2 butterflies ----
        float A1 = C0s[0], B1 = C0s[1], A2 = C0s[2], B2 = C0s[3];
        float Bs = B1 + B2;
        float V  = __builtin_fmaf(w71, Bs, A1 + A2 - B2);
        float SB = bfly4(Bs);
        float SV = bfly4(V);

        z1 = __builtin_fmaf(K8dt, P, z1);      // z += 8dt*P (old P)
        z1 = __builtin_fmaf(-dtdt6, SV, z1);
        P  = __builtin_fmaf(-dt6, SB, P);

        SBp = SB;  SVp = SV;  AL1 = A1;  AL2 = A2;   // lag state

        // ---- S partials (identities sp=uB, sq=uA, pre-f16 f32) ----
        S1p += uB1 + uB2;
        S23p = __builtin_fmaf(cn1, uB1, S23p) + uA1;
        S23p = __builtin_fmaf(cn1 - 1.f, uB2, S23p) + uA2;
        cn1 -= 8.f;
    }

    // ---- tail, steps 96-99: S-ONLY (R35-verified dead-code elim) ----
    {
        const float vm = (quad < 2) ? 1.f : 0.f;
        float z1d = z1 + z1;
        float Pp1  = __builtin_fmaf(cPn1, SBp, P);
        float zp21 = __builtin_fmaf(Kz1a, P, z1d);
        zp21 = __builtin_fmaf(KB1, SBp, zp21);
        zp21 = __builtin_fmaf(KVn1, SVp, zp21);
        float Pp2  = __builtin_fmaf(cPn2, SBp, P);
        float zp22 = __builtin_fmaf(Kz1b, P, z1d);
        zp22 = __builtin_fmaf(KB2, SBp, zp22);
        zp22 = __builtin_fmaf(KVn2, SVp, zp22);

        const float w4m = w4 * vm;
        float e1 = __expf(zp21);
        float r1 = __builtin_amdgcn_rcpf(e1 + 1.f);
        float ua1 = w4m * __builtin_fmaf(-r1, r1, r1);
        float th1 = __builtin_fmaf(-2.f, r1, 1.f);
        float up1 = th1 * ua1;
        float db1 = K2hdt * Pp1;
        float dc1 = __builtin_fmaf(KC1n, AL1, db1);
        float dd1 = __builtin_fmaf(K2dt, Pp1, KC2n * AL1);
        float sA1 = db1 + dc1;
        float sB1 = __builtin_fmaf(2.f, sA1, dd1);
        float u3a1 = 3.f * ua1;
        float uA1 = __builtin_fmaf(-up1, sA1, u3a1);
        float uB1 = __builtin_fmaf(-up1, sB1, u3a1 + u3a1);

        float e2 = __expf(zp22);
        float r2 = __builtin_amdgcn_rcpf(e2 + 1.f);
        float ua2 = w4m * __builtin_fmaf(-r2, r2, r2);
        float th2 = __builtin_fmaf(-2.f, r2, 1.f);
        float up2 = th2 * ua2;
        float db2 = K2hdt * Pp2;
        float dc2 = __builtin_fmaf(KC1n, AL2, db2);
        float dd2 = __builtin_fmaf(K2dt, Pp2, KC2n * AL2);
        float sA2 = db2 + dc2;
        float sB2 = __builtin_fmaf(2.f, sA2, dd2);
        float u3a2 = 3.f * ua2;
        float uA2 = __builtin_fmaf(-up2, sA2, u3a2);
        float uB2 = __builtin_fmaf(-up2, sB2, u3a2 + u3a2);

        S1p += uB1 + uB2;                       // cn1 = 3-j1 here (checked)
        S23p = __builtin_fmaf(cn1, uB1, S23p) + uA1;
        S23p = __builtin_fmaf(cn1 - 1.f, uB2, S23p) + uA2;
    }

    // ---- epilogue: reduce S over quads; buf0 rows {S1, S23, 0, 0} ----
    const float S1f  = bfly4(S1p);
    const float S23f = bfly4(S23p);
    __syncthreads();   // all waves past loop (e=10 buf0-reads complete)
    if (quad == 0) {
        ubuf[c0] = (_Float16)S1f;
        ubuf[US + c0] = (_Float16)S23f;
        ubuf[2 * US + c0] = (_Float16)0.f;
        ubuf[3 * US + c0] = (_Float16)0.f;
    }
    __syncthreads();
    float D10, D20;
    {
        const _Float16* ab = ubuf + sel + kq;
        v4f C0a = {0.f,0.f,0.f,0.f}, C0b = {0.f,0.f,0.f,0.f};
        #pragma unroll
        for (int kk = 0; kk < 8; kk += 2) {
            v8h a0 = *(const v8h*)(ab + 32 * kk);
            v8h a1 = *(const v8h*)(ab + 32 * (kk + 1));
            C0a = __builtin_amdgcn_mfma_f32_16x16x32_f16(a0, wBt0[kk], C0a, 0, 0, 0);
            C0b = __builtin_amdgcn_mfma_f32_16x16x32_f16(a1, wBt0[kk + 1], C0b, 0, 0, 0);
        }
        v4f C0s = C0a + C0b;
        D10 = C0s[0];  D20 = C0s[1];
    }
    const float dt6e = 0.01f / 6.f, dtdt6e = 0.01f * dt6e;
    float pT0 = p0o0 - dt6e * D10;
    float qT0 = q0o0 + 0.01f * 100.f * p0o0 - dtdt6e * D20;

    if (quad == 0)
        ((float2*)(out + (size_t)blk * 512))[c0] = make_float2(qT0, pT0);
}

extern "C" void kernel_launch(void* const* d_in, const int* in_sizes, int n_in,
                              void* d_out, int out_size, void* d_ws, size_t ws_size,
                              hipStream_t stream) {
    const float* x0 = (const float*)d_in[0];
    const float* W1 = (const float*)d_in[1];
    const float* b1 = (const float*)d_in[2];
    const float* W2 = (const float*)d_in[3];
    // d_in[4] = b2: constant offset, no effect on the gradient/dynamics.
    float* out = (float*)d_out;
    hipLaunchKernelGGL(ham_kernel, dim3(256), dim3(1024), 0, stream,
                       x0, W1, b1, W2, out);
}

// Round 19
// 88.325 us; speedup vs baseline: 1.0476x; 1.0476x over previous
//
#include <hip/hip_runtime.h>
#include <stdint.h>

// HamiltonianFlow: x [256, 8, 32, 2] (q,p); H = 0.5*sum(p^2) + MLP(q).
// dq/dt = p, dp/dt = -W u(z), z = W^T q + b1, u = (1-tanh^2(z)).*W2.
// z-space iteration with M = W^T W (R15-R23 verified).
//
// R41 = R40 with the comp-1 WRITE-OFFSET BUG FIXED. R40 NaN'd because it
// assumed "c1 offsets = c0 offsets + 16"; but the row swizzle quad<<3
// takes {0,8,16,24} -- bit 4 is XORed for quad>=2, and c1 = c0|16 has
// bit 4 set, so (c1 ^ (quad<<3)) != (c0 ^ (quad<<3)) + 16 there. Comp-1
// u's landed in wrong slots; MFMA read unwritten LDS -> NaN. Fix:
// cw1 = c1 ^ (quad<<3) computed from first principles (same involution
// the reader applies row-wise; c0/c1 slots always differ in bit 4 ->
// no collisions). Everything else byte-identical to R40.
//
// R40 design: R38 interior (Taylor combos) on an 8-WAVE x 2-TILE
// geometry (R26's layout). Post-Taylor the per-exchange VALU is ~400
// cyc/SIMD but the LDS read burst was 16 waves x 8 ds_read_b128 = 1536
// pipe-cyc/CU -- the critical path. Two tiles share the SAME A-frags
// (combo tile is wave-invariant): 8 waves x 8 reads = 768 cyc, same
// totals for MFMA/writes/exp/VALU per CU; barrier syncs 8 waves;
// 2 waves/SIMD kept. Per-comp math is instruction-identical to R38 =>
// bit-identical absmax expected.
//
// R38: TAYLOR STAGE EVALS - one eval per step: r = rcp(e^{2zp}+1),
// ua = w4*(r-r^2), u' = -tanh*ua (exact); uA = 3ua + u'*(db+dc);
// uB = 6ua + u'*(2(db+dc)+dd); db = 2hdt*Pp, dc = db + KC1n*AL,
// dd = 2dt*Pp + KC2n*AL. Taylor err ~1e-6 << uA's f16 quantum.
// R35/R33: COMBO-LINEARITY - row(2j) = uA_j, row(2j+1) = uB_j; 16 rows
// = 8 steps/exchange, 12 exchanges (H=8 measured optimum); tail steps
// 96-99 are S-ONLY. Exact 8-step advance:
//   z += 8dt*P - dtdt6*SV8;  P -= dt6*SB8
//   SB8 = sum B_j; SV8 = sum (7-j)B_j + sum A_j
//   pred step j: Pp = P - (j/8)dt6*SBp;
//     zp2 = 2z + 2j*dt*P + dtdt6*j(8-j)/8*SBp - dtdt6*(j/4)*SVp
// Lane (quad q) owns steps j1=2q, j2=2q+1 for BOTH comps; V-partial =
// fma(7-j1, B1+B2, A1+A2-B2); 4 bfly4 per 8 steps (2/comp). S: sp=uB,
// sq=uA (pre-f16 f32); tail cn1 = 3-j1.
//
// Substrate: in-kernel W^T staging + M-build (R26 two-tile form), ONE
// barrier per exchange (R24 double-buffer race argument), R30 bank
// swizzle applied PER-COMP, permlane bfly4, mscr (8 x 640 f32) UNION
// ubuf (upool).
// FULL unroll on every reg-array access (R4: dynamic index => scratch).
// Numerics: f16 storage (W, M, uA/uB, S), fp32 MFMA accum + fp32 z/P.

typedef _Float16 v8h __attribute__((ext_vector_type(8)));
typedef float v4f __attribute__((ext_vector_type(4)));

#define NFULL 12  // full 8-step exchanges; steps 96-99 = eval-only tail
#define WS 264    // wldsT row stride (f16): row = one W-COLUMN, 16B-aligned
#define US 272    // ubuf row stride, f16 (544 B == 32 mod 128)

// D(+=C) in VGPRs, A (packed-vector frag) in VGPRs, B (M-frag) from AGPRs.
#define MFMA_AV(C, A, B) \
    asm("v_mfma_f32_16x16x32_f16 %0, %1, %2, %0" : "+v"(C) : "v"(A), "a"(B))

// 4-group butterfly sum over lanes {l, l^16, l^32, l^48}, pure VALU.
__device__ __forceinline__ float bfly4(float x) {
    float a = x, b = x;
    asm("v_permlane16_swap_b32 %0, %1" : "+v"(a), "+v"(b));
    float s = a + b;
    float c = s, d = s;
    asm("v_permlane32_swap_b32 %0, %1" : "+v"(c), "+v"(d));
    return c + d;
}

__global__ __launch_bounds__(512, 2)
void ham_kernel(const float* __restrict__ x0, const float* __restrict__ W1,
                const float* __restrict__ b1, const float* __restrict__ W2,
                float* __restrict__ out)
{
    __shared__ __align__(16)  _Float16 wldsT[256 * WS];  // 135168 B: W^T (f16)
    __shared__ __align__(128) char     upool[20480];     // mscr UNION ubuf
    float*    mscr = (float*)upool;                      // setup only
    _Float16* ubuf = (_Float16*)upool;                   // 2 x 16 rows x US

    const int t = threadIdx.x;
    const int w = t >> 6;          // wave 0..7: owns tiles {2w, 2w+1}
    const int l = t & 63;
    const int quad = l >> 4;       // owns steps 2*quad, 2*quad+1
    const int s = l & 15;          // owned column / A-row
    const int c0 = 32 * w + s;          // comp, tile 2w
    const int c1 = 32 * w + 16 + s;     // comp, tile 2w+1
    const int blk = blockIdx.x;
    const int kq = 8 * quad;
    const int sel = (s & 3) * US;  // prologue/epilogue A-row select (rows 0-3)

    // ---- stage W^T -> LDS f16: wldsT[c][r] = W[r][c] (R26 form) ----
    {
        const int c = t & 255;
        const int rbase = (t >> 8) * 128;   // 2 halves x 128 rows
        #pragma unroll 1
        for (int r0 = 0; r0 < 128; r0 += 8) {
            v8h h;
            #pragma unroll
            for (int j = 0; j < 8; ++j)
                h[j] = (_Float16)W1[(rbase + r0 + j) * 256 + c];
            *(v8h*)(wldsT + c * WS + rbase + r0) = h;   // b128, one-time
        }
    }
    __syncthreads();

    // ---- wF: own-column W^T frags (B-op), contiguous b128 from wldsT ----
    v8h wF0[8], wF1[8];
    #pragma unroll
    for (int kk = 0; kk < 8; ++kk) {
        wF0[kk] = *(const v8h*)(wldsT + c0 * WS + 32 * kk + kq);
        wF1[kk] = *(const v8h*)(wldsT + c1 * WS + 32 * kk + kq);
    }

    // ---- build M = W^T W column-block frags wM0/wM1 (R26 form) ----
    v8h wM0[8], wM1[8];
    float* scr0 = mscr + w * 640;
    float* scr1 = scr0 + 320;
    #pragma unroll
    for (int kb = 0; kb < 16; ++kb) {
        v8h aM[8];   // A[m=s][k=8quad+j] = wldsT[(16kb+s)*WS + 32kk+kq+j]
        #pragma unroll
        for (int kk = 0; kk < 8; ++kk)
            aM[kk] = *(const v8h*)(wldsT + (16 * kb + s) * WS + 32 * kk + kq);
        v4f D0 = {0.f,0.f,0.f,0.f}, D1 = {0.f,0.f,0.f,0.f};
        #pragma unroll
        for (int kk = 0; kk < 8; ++kk) {
            D0 = __builtin_amdgcn_mfma_f32_16x16x32_f16(aM[kk], wF0[kk], D0, 0, 0, 0);
            D1 = __builtin_amdgcn_mfma_f32_16x16x32_f16(aM[kk], wF1[kk], D1, 0, 0, 0);
        }
        *(v4f*)(scr0 + s * 20 + 4 * quad) = D0;
        *(v4f*)(scr1 + s * 20 + 4 * quad) = D1;
        asm volatile("s_waitcnt lgkmcnt(0)" ::: "memory");  // in-wave x-lane
        if ((quad >> 1) == (kb & 1)) {
            #pragma unroll
            for (int j = 0; j < 8; ++j) {
                wM0[kb >> 1][j] = (_Float16)scr0[s * 20 + 8 * (quad & 1) + j];
                wM1[kb >> 1][j] = (_Float16)scr1[s * 20 + 8 * (quad & 1) + j];
            }
        }
        asm volatile("s_waitcnt lgkmcnt(0)" ::: "memory");
    }
    __syncthreads();   // mscr reads (all waves) done before ubuf reuse

    const float b1r0 = b1[c0], b1r1 = b1[c1];
    const float w40 = 4.f * W2[c0], w41 = 4.f * W2[c1];
    float2 qp0 = ((const float2*)(x0 + (size_t)blk * 512))[c0];
    float2 qp1 = ((const float2*)(x0 + (size_t)blk * 512))[c1];
    const float q0o0 = qp0.x, p0o0 = qp0.y;
    const float q0o1 = qp1.x, p0o1 = qp1.y;

    // ---- prologue: buf0 rows {q0, p0, 0, 0} -> z1 (C[0]), P (C[1]) ----
    if (quad == 0) {
        ubuf[c0] = (_Float16)q0o0;          ubuf[c1] = (_Float16)q0o1;
        ubuf[US + c0] = (_Float16)p0o0;     ubuf[US + c1] = (_Float16)p0o1;
        ubuf[2 * US + c0] = (_Float16)0.f;  ubuf[2 * US + c1] = (_Float16)0.f;
        ubuf[3 * US + c0] = (_Float16)0.f;  ubuf[3 * US + c1] = (_Float16)0.f;
    }
    __syncthreads();
    float z10, P0, z11, P1;
    {
        const _Float16* ab = ubuf + sel + kq;
        v4f C0a = {0.f,0.f,0.f,0.f}, C0b = {0.f,0.f,0.f,0.f};
        v4f C1a = {0.f,0.f,0.f,0.f}, C1b = {0.f,0.f,0.f,0.f};
        #pragma unroll
        for (int kk = 0; kk < 8; kk += 2) {
            v8h a0 = *(const v8h*)(ab + 32 * kk);
            v8h a1 = *(const v8h*)(ab + 32 * (kk + 1));
            C0a = __builtin_amdgcn_mfma_f32_16x16x32_f16(a0, wF0[kk], C0a, 0, 0, 0);
            C1a = __builtin_amdgcn_mfma_f32_16x16x32_f16(a0, wF1[kk], C1a, 0, 0, 0);
            C0b = __builtin_amdgcn_mfma_f32_16x16x32_f16(a1, wF0[kk + 1], C0b, 0, 0, 0);
            C1b = __builtin_amdgcn_mfma_f32_16x16x32_f16(a1, wF1[kk + 1], C1b, 0, 0, 0);
        }
        v4f C0s = C0a + C0b, C1s = C1a + C1b;
        z10 = C0s[0] + b1r0;  P0 = C0s[1];
        z11 = C1s[0] + b1r1;  P1 = C1s[1];
    }
    __syncthreads();   // prologue reads done before u(0) overwrites buf0

    const float dt = 0.01f, hdt = 0.005f, dt6 = 0.01f / 6.f;
    const float dtdt6 = dt * dt6, hdt2 = hdt * hdt, dthdt = dt * hdt;
    const float K8dt = 8.f * dt;
    // steps j1 = 2q, j2 = 2q+1; horizon-8 predictor coefs (R29c-verified)
    const float j1 = 2.f * (float)quad, j2 = j1 + 1.f;
    const float cPn1 = -(j1 * 0.125f * dt6), cPn2 = -(j2 * 0.125f * dt6);
    const float Kz1a = 2.f * j1 * dt,        Kz1b = 2.f * j2 * dt;
    const float KB1 = dtdt6 * j1 * (8.f - j1) * 0.125f;
    const float KB2 = dtdt6 * j2 * (8.f - j2) * 0.125f;
    const float KVn1 = -(j1 * dtdt6 * 0.25f), KVn2 = -(j2 * dtdt6 * 0.25f);
    const float K2hdt = 2.f * hdt;
    const float K2dt  = 2.f * dt;
    const float KC1n = -(2.f * hdt2) / 3.f;   // dc: -2hdt^2 * (A/3) folded
    const float KC2n = -(2.f * dthdt) / 3.f;  // dd: -2*dt*hdt * (A/3) folded
    const float w71 = 7.f - j1;               // V = fma(w71, B1+B2, A1+A2-B2)

    // ---- ubuf addressing (R30 bank swizzle, PER-COMP — the R40 fix:
    //      phys col = c ^ ((row>>2)<<3), row>>2 == quad here; bit 4 of
    //      the XOR is live for quad>=2, so c1's offsets are computed
    //      independently, NOT as c0's + 16) ----
    const int cw0 = c0 ^ (quad << 3);
    const int cw1 = c1 ^ (quad << 3);
    const int R0 = 4 * quad;
    const int wo0 = (R0 + 0) * US + cw0;          // row 4q   = uA(j1), comp0
    const int wo1 = (R0 + 1) * US + (cw0 ^ 32);   // row 4q+1 = uB(j1), comp0
    const int wo2 = (R0 + 2) * US + cw0;          // row 4q+2 = uA(j2), comp0
    const int wo3 = (R0 + 3) * US + (cw0 ^ 32);   // row 4q+3 = uB(j2), comp0
    const int xo0 = (R0 + 0) * US + cw1;          // same rows, comp1
    const int xo1 = (R0 + 1) * US + (cw1 ^ 32);
    const int xo2 = (R0 + 2) * US + cw1;
    const int xo3 = (R0 + 3) * US + (cw1 ^ 32);
    const int sx = (s >> 2) & 3;
    const int rbase = s * US + 8 * (quad ^ sx);
    const int sodd = (s & 1) << 5;
    const _Float16* pe = ubuf + rbase + sodd;          // logical even kk
    const _Float16* po = ubuf + rbase + 32 - sodd;     // logical odd  kk

    // lag state per comp (exchange 0: zeros -> benign one-time transient)
    float SBp0 = 0.f, SVp0 = 0.f, AL10 = 0.f, AL20 = 0.f;
    float SBp1 = 0.f, SVp1 = 0.f, AL11 = 0.f, AL21 = 0.f;
    float S1p0 = 0.f, S23p0 = 0.f, S1p1 = 0.f, S23p1 = 0.f;
    float cn1 = 99.f - j1;         // step n1 = 8e + j1; n2 = n1 + 1

    #pragma unroll 1
    for (int e = 0; e < NFULL; ++e) {
        const int bo = (e & 1) * (16 * US);   // double-buffer offset

        // ---- comp0: predict both steps; Taylor combos (R38 path) ----
        float z1d0 = z10 + z10;
        float Pp10  = __builtin_fmaf(cPn1, SBp0, P0);
        float zp210 = __builtin_fmaf(Kz1a, P0, z1d0);
        zp210 = __builtin_fmaf(KB1, SBp0, zp210);
        zp210 = __builtin_fmaf(KVn1, SVp0, zp210);
        float Pp20  = __builtin_fmaf(cPn2, SBp0, P0);
        float zp220 = __builtin_fmaf(Kz1b, P0, z1d0);
        zp220 = __builtin_fmaf(KB2, SBp0, zp220);
        zp220 = __builtin_fmaf(KVn2, SVp0, zp220);

        float e10 = __expf(zp210);
        float r10 = __builtin_amdgcn_rcpf(e10 + 1.f);
        float ua10 = w40 * __builtin_fmaf(-r10, r10, r10);
        float th10 = __builtin_fmaf(-2.f, r10, 1.f);
        float up10 = th10 * ua10;
        float db10 = K2hdt * Pp10;
        float dc10 = __builtin_fmaf(KC1n, AL10, db10);
        float dd10 = __builtin_fmaf(K2dt, Pp10, KC2n * AL10);
        float sA10 = db10 + dc10;
        float sB10 = __builtin_fmaf(2.f, sA10, dd10);
        float u3a10 = 3.f * ua10;
        float uA10 = __builtin_fmaf(-up10, sA10, u3a10);
        float uB10 = __builtin_fmaf(-up10, sB10, u3a10 + u3a10);

        float e20 = __expf(zp220);
        float r20 = __builtin_amdgcn_rcpf(e20 + 1.f);
        float ua20 = w40 * __builtin_fmaf(-r20, r20, r20);
        float th20 = __builtin_fmaf(-2.f, r20, 1.f);
        float up20 = th20 * ua20;
        float db20 = K2hdt * Pp20;
        float dc20 = __builtin_fmaf(KC1n, AL20, db20);
        float dd20 = __builtin_fmaf(K2dt, Pp20, KC2n * AL20);
        float sA20 = db20 + dc20;
        float sB20 = __builtin_fmaf(2.f, sA20, dd20);
        float u3a20 = 3.f * ua20;
        float uA20 = __builtin_fmaf(-up20, sA20, u3a20);
        float uB20 = __builtin_fmaf(-up20, sB20, u3a20 + u3a20);

        // ---- comp1: same, state 1 ----
        float z1d1 = z11 + z11;
        float Pp11  = __builtin_fmaf(cPn1, SBp1, P1);
        float zp211 = __builtin_fmaf(Kz1a, P1, z1d1);
        zp211 = __builtin_fmaf(KB1, SBp1, zp211);
        zp211 = __builtin_fmaf(KVn1, SVp1, zp211);
        float Pp21  = __builtin_fmaf(cPn2, SBp1, P1);
        float zp221 = __builtin_fmaf(Kz1b, P1, z1d1);
        zp221 = __builtin_fmaf(KB2, SBp1, zp221);
        zp221 = __builtin_fmaf(KVn2, SVp1, zp221);

        float e11 = __expf(zp211);
        float r11 = __builtin_amdgcn_rcpf(e11 + 1.f);
        float ua11 = w41 * __builtin_fmaf(-r11, r11, r11);
        float th11 = __builtin_fmaf(-2.f, r11, 1.f);
        float up11 = th11 * ua11;
        float db11 = K2hdt * Pp11;
        float dc11 = __builtin_fmaf(KC1n, AL11, db11);
        float dd11 = __builtin_fmaf(K2dt, Pp11, KC2n * AL11);
        float sA11 = db11 + dc11;
        float sB11 = __builtin_fmaf(2.f, sA11, dd11);
        float u3a11 = 3.f * ua11;
        float uA11 = __builtin_fmaf(-up11, sA11, u3a11);
        float uB11 = __builtin_fmaf(-up11, sB11, u3a11 + u3a11);

        float e21 = __expf(zp221);
        float r21 = __builtin_amdgcn_rcpf(e21 + 1.f);
        float ua21 = w41 * __builtin_fmaf(-r21, r21, r21);
        float th21 = __builtin_fmaf(-2.f, r21, 1.f);
        float up21 = th21 * ua21;
        float db21 = K2hdt * Pp21;
        float dc21 = __builtin_fmaf(KC1n, AL21, db21);
        float dd21 = __builtin_fmaf(K2dt, Pp21, KC2n * AL21);
        float sA21 = db21 + dc21;
        float sB21 = __builtin_fmaf(2.f, sA21, dd21);
        float u3a21 = 3.f * ua21;
        float uA21 = __builtin_fmaf(-up21, sA21, u3a21);
        float uB21 = __builtin_fmaf(-up21, sB21, u3a21 + u3a21);

        ubuf[bo + wo0] = (_Float16)uA10;  ubuf[bo + xo0] = (_Float16)uA11;
        ubuf[bo + wo1] = (_Float16)uB10;  ubuf[bo + xo1] = (_Float16)uB11;
        ubuf[bo + wo2] = (_Float16)uA20;  ubuf[bo + xo2] = (_Float16)uA21;
        ubuf[bo + wo3] = (_Float16)uB20;  ubuf[bo + xo3] = (_Float16)uB21;
        __syncthreads();   // the ONLY barrier per exchange (8 steps)

        // ---- ONE shared-A MFMA block: both comps' {A1,B1,A2,B2} ----
        v4f C0s, C1s;
        {
            v4f C0a = {0.f,0.f,0.f,0.f}, C0b = {0.f,0.f,0.f,0.f};
            v4f C1a = {0.f,0.f,0.f,0.f}, C1b = {0.f,0.f,0.f,0.f};
            #pragma unroll
            for (int kk = 0; kk < 8; kk += 2) {
                v8h a0 = *(const v8h*)(pe + bo + 32 * kk);
                v8h a1 = *(const v8h*)(po + bo + 32 * kk);
                MFMA_AV(C0a, a0, wM0[kk]);
                MFMA_AV(C1a, a0, wM1[kk]);
                MFMA_AV(C0b, a1, wM0[kk + 1]);
                MFMA_AV(C1b, a1, wM1[kk + 1]);
            }
            C0s = C0a + C0b;  C1s = C1a + C1b;
        }
        // no second barrier: next exchange writes the OTHER buffer (R24).

        // ---- EXACT 8-step advance via 2 butterflies per comp ----
        float A10 = C0s[0], B10 = C0s[1], A20 = C0s[2], B20 = C0s[3];
        float Bs0 = B10 + B20;
        float V0  = __builtin_fmaf(w71, Bs0, A10 + A20 - B20);
        float SB0 = bfly4(Bs0);
        float SV0 = bfly4(V0);
        z10 = __builtin_fmaf(K8dt, P0, z10);
        z10 = __builtin_fmaf(-dtdt6, SV0, z10);
        P0  = __builtin_fmaf(-dt6, SB0, P0);
        SBp0 = SB0;  SVp0 = SV0;  AL10 = A10;  AL20 = A20;

        float A11 = C1s[0], B11 = C1s[1], A21 = C1s[2], B21 = C1s[3];
        float Bs1 = B11 + B21;
        float V1  = __builtin_fmaf(w71, Bs1, A11 + A21 - B21);
        float SB1 = bfly4(Bs1);
        float SV1 = bfly4(V1);
        z11 = __builtin_fmaf(K8dt, P1, z11);
        z11 = __builtin_fmaf(-dtdt6, SV1, z11);
        P1  = __builtin_fmaf(-dt6, SB1, P1);
        SBp1 = SB1;  SVp1 = SV1;  AL11 = A11;  AL21 = A21;

        // ---- S partials (identities sp=uB, sq=uA, pre-f16 f32) ----
        S1p0 += uB10 + uB20;
        S23p0 = __builtin_fmaf(cn1, uB10, S23p0) + uA10;
        S23p0 = __builtin_fmaf(cn1 - 1.f, uB20, S23p0) + uA20;
        S1p1 += uB11 + uB21;
        S23p1 = __builtin_fmaf(cn1, uB11, S23p1) + uA11;
        S23p1 = __builtin_fmaf(cn1 - 1.f, uB21, S23p1) + uA21;
        cn1 -= 8.f;
    }

    // ---- tail, steps 96-99: S-ONLY (R35-verified dead-code elim) ----
    {
        const float vm = (quad < 2) ? 1.f : 0.f;
        const float w4m0 = w40 * vm, w4m1 = w41 * vm;

        float z1d0 = z10 + z10;
        float Pp10  = __builtin_fmaf(cPn1, SBp0, P0);
        float zp210 = __builtin_fmaf(Kz1a, P0, z1d0);
        zp210 = __builtin_fmaf(KB1, SBp0, zp210);
        zp210 = __builtin_fmaf(KVn1, SVp0, zp210);
        float Pp20  = __builtin_fmaf(cPn2, SBp0, P0);
        float zp220 = __builtin_fmaf(Kz1b, P0, z1d0);
        zp220 = __builtin_fmaf(KB2, SBp0, zp220);
        zp220 = __builtin_fmaf(KVn2, SVp0, zp220);
        float e10 = __expf(zp210);
        float r10 = __builtin_amdgcn_rcpf(e10 + 1.f);
        float ua10 = w4m0 * __builtin_fmaf(-r10, r10, r10);
        float th10 = __builtin_fmaf(-2.f, r10, 1.f);
        float up10 = th10 * ua10;
        float db10 = K2hdt * Pp10;
        float dc10 = __builtin_fmaf(KC1n, AL10, db10);
        float dd10 = __builtin_fmaf(K2dt, Pp10, KC2n * AL10);
        float sA10 = db10 + dc10;
        float sB10 = __builtin_fmaf(2.f, sA10, dd10);
        float u3a10 = 3.f * ua10;
        float uA10 = __builtin_fmaf(-up10, sA10, u3a10);
        float uB10 = __builtin_fmaf(-up10, sB10, u3a10 + u3a10);
        float e20 = __expf(zp220);
        float r20 = __builtin_amdgcn_rcpf(e20 + 1.f);
        float ua20 = w4m0 * __builtin_fmaf(-r20, r20, r20);
        float th20 = __builtin_fmaf(-2.f, r20, 1.f);
        float up20 = th20 * ua20;
        float db20 = K2hdt * Pp20;
        float dc20 = __builtin_fmaf(KC1n, AL20, db20);
        float dd20 = __builtin_fmaf(K2dt, Pp20, KC2n * AL20);
        float sA20 = db20 + dc20;
        float sB20 = __builtin_fmaf(2.f, sA20, dd20);
        float u3a20 = 3.f * ua20;
        float uA20 = __builtin_fmaf(-up20, sA20, u3a20);
        float uB20 = __builtin_fmaf(-up20, sB20, u3a20 + u3a20);
        S1p0 += uB10 + uB20;
        S23p0 = __builtin_fmaf(cn1, uB10, S23p0) + uA10;
        S23p0 = __builtin_fmaf(cn1 - 1.f, uB20, S23p0) + uA20;

        float z1d1 = z11 + z11;
        float Pp11  = __builtin_fmaf(cPn1, SBp1, P1);
        float zp211 = __builtin_fmaf(Kz1a, P1, z1d1);
        zp211 = __builtin_fmaf(KB1, SBp1, zp211);
        zp211 = __builtin_fmaf(KVn1, SVp1, zp211);
        float Pp21  = __builtin_fmaf(cPn2, SBp1, P1);
        float zp221 = __builtin_fmaf(Kz1b, P1, z1d1);
        zp221 = __builtin_fmaf(KB2, SBp1, zp221);
        zp221 = __builtin_fmaf(KVn2, SVp1, zp221);
        float e11 = __expf(zp211);
        float r11 = __builtin_amdgcn_rcpf(e11 + 1.f);
        float ua11 = w4m1 * __builtin_fmaf(-r11, r11, r11);
        float th11 = __builtin_fmaf(-2.f, r11, 1.f);
        float up11 = th11 * ua11;
        float db11 = K2hdt * Pp11;
        float dc11 = __builtin_fmaf(KC1n, AL11, db11);
        float dd11 = __builtin_fmaf(K2dt, Pp11, KC2n * AL11);
        float sA11 = db11 + dc11;
        float sB11 = __builtin_fmaf(2.f, sA11, dd11);
        float u3a11 = 3.f * ua11;
        float uA11 = __builtin_fmaf(-up11, sA11, u3a11);
        float uB11 = __builtin_fmaf(-up11, sB11, u3a11 + u3a11);
        float e21 = __expf(zp221);
        float r21 = __builtin_amdgcn_rcpf(e21 + 1.f);
        float ua21 = w4m1 * __builtin_fmaf(-r21, r21, r21);
        float th21 = __builtin_fmaf(-2.f, r21, 1.f);
        float up21 = th21 * ua21;
        float db21 = K2hdt * Pp21;
        float dc21 = __builtin_fmaf(KC1n, AL21, db21);
        float dd21 = __builtin_fmaf(K2dt, Pp21, KC2n * AL21);
        float sA21 = db21 + dc21;
        float sB21 = __builtin_fmaf(2.f, sA21, dd21);
        float u3a21 = 3.f * ua21;
        float uA21 = __builtin_fmaf(-up21, sA21, u3a21);
        float uB21 = __builtin_fmaf(-up21, sB21, u3a21 + u3a21);
        S1p1 += uB11 + uB21;
        S23p1 = __builtin_fmaf(cn1, uB11, S23p1) + uA11;
        S23p1 = __builtin_fmaf(cn1 - 1.f, uB21, S23p1) + uA21;
    }

    // ---- epilogue: reduce S; buf0 rows {S1, S23, 0, 0} both comps ----
    const float S1f0  = bfly4(S1p0),  S1f1  = bfly4(S1p1);
    const float S23f0 = bfly4(S23p0), S23f1 = bfly4(S23p1);
    __syncthreads();   // all waves past loop (e=10 buf0-reads complete)
    if (quad == 0) {
        ubuf[c0] = (_Float16)S1f0;          ubuf[c1] = (_Float16)S1f1;
        ubuf[US + c0] = (_Float16)S23f0;    ubuf[US + c1] = (_Float16)S23f1;
        ubuf[2 * US + c0] = (_Float16)0.f;  ubuf[2 * US + c1] = (_Float16)0.f;
        ubuf[3 * US + c0] = (_Float16)0.f;  ubuf[3 * US + c1] = (_Float16)0.f;
    }
    __syncthreads();
    // wBt[kk][j] = W[c][32kk+kq+j] = wldsT[(32kk+kq+j)*WS + c]  (post-loop:
    // R39 measured the pre-loop hoist at -4.6us; keep R38 placement)
    v8h wBt0[8], wBt1[8];
    #pragma unroll
    for (int kk = 0; kk < 8; ++kk)
        #pragma unroll
        for (int j = 0; j < 8; ++j) {
            wBt0[kk][j] = wldsT[(32 * kk + kq + j) * WS + c0];
            wBt1[kk][j] = wldsT[(32 * kk + kq + j) * WS + c1];
        }
    float D10, D20, D11, D21;
    {
        const _Float16* ab = ubuf + sel + kq;
        v4f C0a = {0.f,0.f,0.f,0.f}, C0b = {0.f,0.f,0.f,0.f};
        v4f C1a = {0.f,0.f,0.f,0.f}, C1b = {0.f,0.f,0.f,0.f};
        #pragma unroll
        for (int kk = 0; kk < 8; kk += 2) {
            v8h a0 = *(const v8h*)(ab + 32 * kk);
            v8h a1 = *(const v8h*)(ab + 32 * (kk + 1));
            C0a = __builtin_amdgcn_mfma_f32_16x16x32_f16(a0, wBt0[kk], C0a, 0, 0, 0);
            C1a = __builtin_amdgcn_mfma_f32_16x16x32_f16(a0, wBt1[kk], C1a, 0, 0, 0);
            C0b = __builtin_amdgcn_mfma_f32_16x16x32_f16(a1, wBt0[kk + 1], C0b, 0, 0, 0);
            C1b = __builtin_amdgcn_mfma_f32_16x16x32_f16(a1, wBt1[kk + 1], C1b, 0, 0, 0);
        }
        v4f C0s = C0a + C0b, C1s = C1a + C1b;
        D10 = C0s[0];  D20 = C0s[1];
        D11 = C1s[0];  D21 = C1s[1];
    }
    const float dt6e = 0.01f / 6.f, dtdt6e = 0.01f * dt6e;
    float pT0 = p0o0 - dt6e * D10;
    float qT0 = q0o0 + 0.01f * 100.f * p0o0 - dtdt6e * D20;
    float pT1 = p0o1 - dt6e * D11;
    float qT1 = q0o1 + 0.01f * 100.f * p0o1 - dtdt6e * D21;

    if (quad == 0) {
        ((float2*)(out + (size_t)blk * 512))[c0] = make_float2(qT0, pT0);
        ((float2*)(out + (size_t)blk * 512))[c1] = make_float2(qT1, pT1);
    }
}

extern "C" void kernel_launch(void* const* d_in, const int* in_sizes, int n_in,
                              void* d_out, int out_size, void* d_ws, size_t ws_size,
                              hipStream_t stream) {
    const float* x0 = (const float*)d_in[0];
    const float* W1 = (const float*)d_in[1];
    const float* b1 = (const float*)d_in[2];
    const float* W2 = (const float*)d_in[3];
    // d_in[4] = b2: constant offset, no effect on the gradient/dynamics.
    float* out = (float*)d_out;
    hipLaunchKernelGGL(ham_kernel, dim3(256), dim3(512), 0, stream,
                       x0, W1, b1, W2, out);
}